// Round 6
// baseline (230.638 us; speedup 1.0000x reference)
//
#include <hip/hip_runtime.h>
#include <math.h>

#define NB 8192
#define NI 12288
#define H0 256
#define H1 32
#define H2 32
#define MAXA 256
#define OUT_SCALE 300.0f
#define WDL_SCALE 200.0f

typedef float f32x4 __attribute__((ext_vector_type(4)));

// ws layout:
//   [0)                ftT      : NI*H0 floats           (12,582,912 B)
//   [FTT_B)            counters : 2*NB ints              (65,536 B)
//   [FTT_B+CNT_B)      indices  : 2*NB*MAXA ints         (16,777,216 B)
#define FTT_B  ((size_t)NI * H0 * 4)
#define CNT_B  ((size_t)2 * NB * 4)
#define IDX_B  ((size_t)2 * NB * MAXA * 4)
#define WS_NEED (FTT_B + CNT_B + IDX_B)

// ---------------------------------------------------------------------------
// Kernel 0: zero the per-row counters (harness does not re-poison ws)
// ---------------------------------------------------------------------------
__global__ __launch_bounds__(256) void nnue_zero_cnt(int* __restrict__ cnt)
{
    const int i = blockIdx.x * 256 + threadIdx.x;
    if (i < 2 * NB) cnt[i] = 0;
}

// ---------------------------------------------------------------------------
// Kernel 1: tiled transpose ft_w [H0][NI] -> ftT [NI][H0]
// ---------------------------------------------------------------------------
__global__ __launch_bounds__(256) void nnue_ft_transpose(
    const float* __restrict__ src, float* __restrict__ dst)
{
    __shared__ float tile[64][65];
    const int bx = blockIdx.x;
    const int by = blockIdx.y;
    const int tx = threadIdx.x;              // 64
    const int ty = threadIdx.y;              // 4
    const int col = bx * 64 + tx;
    for (int j = ty; j < 64; j += 4)
        tile[j][tx] = src[(size_t)(by * 64 + j) * NI + col];
    __syncthreads();
    const int h = by * 64 + tx;
    for (int j = ty; j < 64; j += 4)
        dst[(size_t)(bx * 64 + j) * H0 + h] = tile[tx][j];
}

// ---------------------------------------------------------------------------
// Kernel 2: pure streaming scan. grid (2048, 2); block handles 4 rows of one
// perspective (12288 f32x4). Zero barriers; 8 loads in flight per thread.
// Nonzero indices compacted to ws via global atomics (order irrelevant).
// ---------------------------------------------------------------------------
__global__ __launch_bounds__(256) void nnue_scan(
    const float* __restrict__ wf, const float* __restrict__ bf,
    int* __restrict__ cnt, int* __restrict__ idx)
{
    const int t     = threadIdx.x;
    const int bid   = blockIdx.x;            // 0..2047
    const int persp = blockIdx.y;            // 0=white 1=black
    const float* src = persp ? bf : wf;
    int* mycnt = cnt + persp * NB;
    int* myidx = idx + (size_t)persp * NB * MAXA;

    const f32x4* s4 = (const f32x4*)src + (size_t)bid * 12288;  // 4 rows
    #pragma unroll 1
    for (int it = 0; it < 6; ++it) {
        f32x4 v[8];
        #pragma unroll
        for (int u = 0; u < 8; ++u)
            v[u] = __builtin_nontemporal_load(&s4[it * 2048 + u * 256 + t]);
        #pragma unroll
        for (int u = 0; u < 8; ++u) {
            int m = (v[u].x != 0.f ? 1 : 0) | (v[u].y != 0.f ? 2 : 0)
                  | (v[u].z != 0.f ? 4 : 0) | (v[u].w != 0.f ? 8 : 0);
            if (m) {
                const int local = it * 2048 + u * 256 + t;   // [0,12288)
                const int row_l = local / 3072;              // 0..3
                const int pos   = (local - row_l * 3072) * 4;
                const int row   = bid * 4 + row_l;
                while (m) {
                    const int b = __ffs(m) - 1;
                    m &= m - 1;
                    const int off = atomicAdd(&mycnt[row], 1);
                    if (off < MAXA)
                        myidx[(size_t)row * MAXA + off] = pos + b;
                }
            }
        }
    }
}

// ---------------------------------------------------------------------------
// Kernel 3: per-row gather + MLP. One 256-thread block per batch row.
//   idx lists -> LDS; wave-parallel gather (wave w: features w, w+4, ...;
//   lane l owns units 4l..4l+3) -> LDS combine -> concat -> MLP -> sigmoid
// ---------------------------------------------------------------------------
__global__ __launch_bounds__(256) void nnue_fwd2(
    const int* __restrict__ cnt, const int* __restrict__ idx,
    const int* __restrict__ side,
    const float* __restrict__ ft,        // ftT [NI][H0]
    const float* __restrict__ ft_b,
    const float* __restrict__ l1_w, const float* __restrict__ l1_b,
    const float* __restrict__ l2_w, const float* __restrict__ l2_b,
    const float* __restrict__ l3_w, const float* __restrict__ l3_b,
    float* __restrict__ out)
{
    __shared__ int   idxW[MAXA], idxB[MAXA];
    __shared__ float pacc[4][2][H0] __attribute__((aligned(16)));
    __shared__ float o0[2 * H0];
    __shared__ float o1[H1];

    const int row = blockIdx.x;
    const int t   = threadIdx.x;
    const int nW  = min(cnt[row], MAXA);
    const int nB  = min(cnt[NB + row], MAXA);

    idxW[t] = idx[(size_t)row * MAXA + t];                 // coalesced copy
    idxB[t] = idx[(size_t)(NB + row) * MAXA + t];
    __syncthreads();

    const int w = t >> 6, l = t & 63;
    f32x4 aw0 = {0.f, 0.f, 0.f, 0.f}, aw1 = {0.f, 0.f, 0.f, 0.f};
    int i = w;
    for (; i + 4 < nW; i += 8) {
        const f32x4 r0 = *(const f32x4*)(ft + (size_t)idxW[i] * H0 + 4 * l);
        const f32x4 r1 = *(const f32x4*)(ft + (size_t)idxW[i + 4] * H0 + 4 * l);
        aw0 += r0; aw1 += r1;
    }
    if (i < nW)
        aw0 += *(const f32x4*)(ft + (size_t)idxW[i] * H0 + 4 * l);

    f32x4 ab0 = {0.f, 0.f, 0.f, 0.f}, ab1 = {0.f, 0.f, 0.f, 0.f};
    i = w;
    for (; i + 4 < nB; i += 8) {
        const f32x4 r0 = *(const f32x4*)(ft + (size_t)idxB[i] * H0 + 4 * l);
        const f32x4 r1 = *(const f32x4*)(ft + (size_t)idxB[i + 4] * H0 + 4 * l);
        ab0 += r0; ab1 += r1;
    }
    if (i < nB)
        ab0 += *(const f32x4*)(ft + (size_t)idxB[i] * H0 + 4 * l);

    *(f32x4*)&pacc[w][0][4 * l] = aw0 + aw1;
    *(f32x4*)&pacc[w][1][4 * l] = ab0 + ab1;
    __syncthreads();

    const float ftb  = ft_b[t];
    const float accW = ftb + ((pacc[0][0][t] + pacc[1][0][t]) + (pacc[2][0][t] + pacc[3][0][t]));
    const float accB = ftb + ((pacc[0][1][t] + pacc[1][1][t]) + (pacc[2][1][t] + pacc[3][1][t]));
    const bool s = side[row] != 0;
    const float wv = fminf(fmaxf(accW, 0.f), 1.f);
    const float bv = fminf(fmaxf(accB, 0.f), 1.f);
    o0[t]      = s ? wv : bv;
    o0[t + H0] = s ? bv : wv;
    __syncthreads();

    {
        const int j = t >> 3, p = t & 7;
        const float* wrow = l1_w + j * (2 * H0);
        float sum = 0.f;
        #pragma unroll
        for (int m = 0; m < 64; ++m) {
            const int k = p + 8 * m;
            sum += wrow[k] * o0[k];
        }
        sum += __shfl_xor(sum, 1);
        sum += __shfl_xor(sum, 2);
        sum += __shfl_xor(sum, 4);
        if (p == 0) o1[j] = fminf(fmaxf(sum + l1_b[j], 0.f), 1.f);
    }
    __syncthreads();

    if (t < 32) {
        const float* wrow = l2_w + t * H1;
        float sum2 = 0.f;
        #pragma unroll
        for (int k = 0; k < H1; ++k) sum2 += wrow[k] * o1[k];
        const float o2v = fminf(fmaxf(sum2 + l2_b[t], 0.f), 1.f);
        float part = o2v * l3_w[t];
        part += __shfl_xor(part, 1);
        part += __shfl_xor(part, 2);
        part += __shfl_xor(part, 4);
        part += __shfl_xor(part, 8);
        part += __shfl_xor(part, 16);
        if (t == 0) {
            const float o3 = (part + l3_b[0]) * OUT_SCALE;
            out[row] = 1.f / (1.f + __expf(-o3 / WDL_SCALE));
        }
    }
}

// ---------------------------------------------------------------------------
// Fallback (ws too small): round-5 fused kernel, untransposed strided gather.
// ---------------------------------------------------------------------------
__global__ __launch_bounds__(256) void nnue_fused_fallback(
    const float* __restrict__ wf, const float* __restrict__ bf,
    const int* __restrict__ side,
    const float* __restrict__ ft,        // ft_w [H0][NI]
    const float* __restrict__ ft_b,
    const float* __restrict__ l1_w, const float* __restrict__ l1_b,
    const float* __restrict__ l2_w, const float* __restrict__ l2_b,
    const float* __restrict__ l3_w, const float* __restrict__ l3_b,
    float* __restrict__ out)
{
    __shared__ int   idxW[MAXA], idxB[MAXA];
    __shared__ int   cnts[2];
    __shared__ float o0[2 * H0];
    __shared__ float o1[H1];

    const int row = blockIdx.x;
    const int t   = threadIdx.x;
    if (t < 2) cnts[t] = 0;
    __syncthreads();

    const f32x4* wf4 = (const f32x4*)(wf + (size_t)row * NI);
    const f32x4* bf4 = (const f32x4*)(bf + (size_t)row * NI);
    const float ftb = ft_b[t];

    for (int half = 0; half < 2; ++half) {
        const f32x4* p4 = half ? bf4 : wf4;
        int* lst = half ? idxB : idxW;
        f32x4 v[12];
        #pragma unroll
        for (int k = 0; k < 12; ++k)
            v[k] = __builtin_nontemporal_load(&p4[t + k * 256]);
        #pragma unroll
        for (int k = 0; k < 12; ++k) {
            const int base = (t + k * 256) * 4;
            int m = (v[k].x != 0.f ? 1 : 0) | (v[k].y != 0.f ? 2 : 0)
                  | (v[k].z != 0.f ? 4 : 0) | (v[k].w != 0.f ? 8 : 0);
            while (m) {
                const int b = __ffs(m) - 1;
                m &= m - 1;
                lst[atomicAdd(&cnts[half], 1)] = base + b;
            }
        }
    }
    __syncthreads();

    const int nW = cnts[0], nB = cnts[1];
    float accW = ftb, accB = ftb;
    const float* ftr = ft + (size_t)t * NI;
    for (int j = 0; j < nW; ++j) accW += ftr[idxW[j]];
    for (int j = 0; j < nB; ++j) accB += ftr[idxB[j]];

    const bool s = side[row] != 0;
    const float wv = fminf(fmaxf(accW, 0.f), 1.f);
    const float bv = fminf(fmaxf(accB, 0.f), 1.f);
    o0[t]      = s ? wv : bv;
    o0[t + H0] = s ? bv : wv;
    __syncthreads();

    {
        const int j = t >> 3, p = t & 7;
        const float* wrow = l1_w + j * (2 * H0);
        float sum = 0.f;
        #pragma unroll
        for (int m = 0; m < 64; ++m) sum += wrow[p + 8 * m] * o0[p + 8 * m];
        sum += __shfl_xor(sum, 1);
        sum += __shfl_xor(sum, 2);
        sum += __shfl_xor(sum, 4);
        if (p == 0) o1[j] = fminf(fmaxf(sum + l1_b[j], 0.f), 1.f);
    }
    __syncthreads();

    if (t < 32) {
        const float* wrow = l2_w + t * H1;
        float sum2 = 0.f;
        #pragma unroll
        for (int k = 0; k < H1; ++k) sum2 += wrow[k] * o1[k];
        const float o2v = fminf(fmaxf(sum2 + l2_b[t], 0.f), 1.f);
        float part = o2v * l3_w[t];
        part += __shfl_xor(part, 1);
        part += __shfl_xor(part, 2);
        part += __shfl_xor(part, 4);
        part += __shfl_xor(part, 8);
        part += __shfl_xor(part, 16);
        if (t == 0) {
            const float o3 = (part + l3_b[0]) * OUT_SCALE;
            out[row] = 1.f / (1.f + __expf(-o3 / WDL_SCALE));
        }
    }
}

extern "C" void kernel_launch(void* const* d_in, const int* in_sizes, int n_in,
                              void* d_out, int out_size, void* d_ws, size_t ws_size,
                              hipStream_t stream) {
    const float* wf   = (const float*)d_in[0];
    const float* bf   = (const float*)d_in[1];
    const int*   side = (const int*)d_in[2];
    const float* ft_w = (const float*)d_in[3];
    const float* ft_b = (const float*)d_in[4];
    const float* l1_w = (const float*)d_in[5];
    const float* l1_b = (const float*)d_in[6];
    const float* l2_w = (const float*)d_in[7];
    const float* l2_b = (const float*)d_in[8];
    const float* l3_w = (const float*)d_in[9];
    const float* l3_b = (const float*)d_in[10];
    float*       out  = (float*)d_out;

    if (ws_size >= WS_NEED) {
        float* ftT = (float*)d_ws;
        int*   cnt = (int*)((char*)d_ws + FTT_B);
        int*   idx = (int*)((char*)d_ws + FTT_B + CNT_B);

        nnue_zero_cnt<<<(2 * NB + 255) / 256, 256, 0, stream>>>(cnt);
        nnue_scan<<<dim3(NB / 4, 2), 256, 0, stream>>>(wf, bf, cnt, idx);
        nnue_ft_transpose<<<dim3(NI / 64, H0 / 64), dim3(64, 4), 0, stream>>>(ft_w, ftT);
        nnue_fwd2<<<NB, 256, 0, stream>>>(cnt, idx, side, ftT, ft_b,
                                          l1_w, l1_b, l2_w, l2_b, l3_w, l3_b, out);
    } else {
        nnue_fused_fallback<<<NB, 256, 0, stream>>>(wf, bf, side, ft_w, ft_b,
                                                    l1_w, l1_b, l2_w, l2_b,
                                                    l3_w, l3_b, out);
    }
}

// Round 7
// 196.333 us; speedup vs baseline: 1.1747x; 1.1747x over previous
//
#include <hip/hip_runtime.h>
#include <math.h>

#define NB 8192
#define NI 12288
#define H0 256
#define H1 32
#define H2 32
#define MAXA 256
#define OUT_SCALE 300.0f
#define WDL_SCALE 200.0f

typedef float f32x4 __attribute__((ext_vector_type(4)));

// ws layout: ftT [NI][H0] | l1T [512][32] | l2T [32][32]
#define FTT_B  ((size_t)NI * H0 * 4)          // 12,582,912 B
#define L1T_B  ((size_t)2 * H0 * H1 * 4)      // 65,536 B
#define L2T_B  ((size_t)H1 * H2 * 4)          // 4,096 B
#define WS_NEED (FTT_B + L1T_B + L2T_B)

// ---------------------------------------------------------------------------
// Kernel 1: tiled transpose ft_w [H0][NI] -> ftT [NI][H0]
// ---------------------------------------------------------------------------
__global__ __launch_bounds__(256) void nnue_ft_transpose(
    const float* __restrict__ src, float* __restrict__ dst)
{
    __shared__ float tile[64][65];
    const int bx = blockIdx.x;
    const int by = blockIdx.y;
    const int tx = threadIdx.x;              // 64
    const int ty = threadIdx.y;              // 4
    const int col = bx * 64 + tx;
    for (int j = ty; j < 64; j += 4)
        tile[j][tx] = src[(size_t)(by * 64 + j) * NI + col];
    __syncthreads();
    const int h = by * 64 + tx;
    for (int j = ty; j < 64; j += 4)
        dst[(size_t)(bx * 64 + j) * H0 + h] = tile[tx][j];
}

// ---------------------------------------------------------------------------
// Kernel 1b: transpose the small MLP weights: l1T[k*32+j]=l1_w[j*512+k],
// l2T[k*32+j]=l2_w[j*32+k]  (one-off, ~17k elements)
// ---------------------------------------------------------------------------
__global__ __launch_bounds__(256) void nnue_small_transpose(
    const float* __restrict__ l1_w, const float* __restrict__ l2_w,
    float* __restrict__ l1T, float* __restrict__ l2T)
{
    const int i = blockIdx.x * 256 + threadIdx.x;
    if (i < 2 * H0 * H1) {                   // 16384
        const int k = i >> 5, j = i & 31;
        l1T[i] = l1_w[j * (2 * H0) + k];
    }
    const int i2 = i - 2 * H0 * H1;
    if (i2 >= 0 && i2 < H1 * H2) {           // 1024
        const int k = i2 >> 5, j = i2 & 31;
        l2T[i2] = l2_w[j * H1 + k];
    }
}

// ---------------------------------------------------------------------------
// Kernel 2: wave-per-row fused forward. 2048 blocks x 256 threads; wave w of
// block b owns batch row b*4+w. ZERO __syncthreads: all LDS traffic is
// wave-private (within-wave ordering via lgkmcnt only), so vector loads are
// never drained at a barrier and waves overlap freely.
// ---------------------------------------------------------------------------
__global__ __launch_bounds__(256) void nnue_fwd_wave(
    const float* __restrict__ wf, const float* __restrict__ bf,
    const int* __restrict__ side,
    const float* __restrict__ ft,        // ftT [NI][H0]
    const float* __restrict__ ft_b,
    const float* __restrict__ l1T, const float* __restrict__ l1_b,
    const float* __restrict__ l2T, const float* __restrict__ l2_b,
    const float* __restrict__ l3_w, const float* __restrict__ l3_b,
    float* __restrict__ out)
{
    __shared__ int   idx[4][2][MAXA];        // per-wave index lists
    __shared__ int   cnt[4][2];
    __shared__ float o0s[4][2 * H0];         // per-wave concat activations
    __shared__ float o1s[4][H1];

    const int t = threadIdx.x;
    const int w = t >> 6;                    // wave in block
    const int l = t & 63;                    // lane
    const int row = blockIdx.x * 4 + w;

    if (l == 0) { cnt[w][0] = 0; cnt[w][1] = 0; }

    // ---- scan both perspectives: 48 f32x4/lane each, double-buffered 8-deep
    #pragma unroll 1
    for (int p = 0; p < 2; ++p) {
        const float* src = p ? bf : wf;
        const f32x4* s4 = (const f32x4*)(src + (size_t)row * NI);
        int* myidx = idx[w][p];
        int* mycnt = &cnt[w][p];

        auto proc = [&](const f32x4* v, int cbase) {
            #pragma unroll
            for (int u = 0; u < 8; ++u) {
                const int e = cbase * 512 + u * 64 + l;   // f32x4 idx in row
                int m = (v[u].x != 0.f ? 1 : 0) | (v[u].y != 0.f ? 2 : 0)
                      | (v[u].z != 0.f ? 4 : 0) | (v[u].w != 0.f ? 8 : 0);
                while (m) {
                    const int b = __ffs(m) - 1;
                    m &= m - 1;
                    const int off = atomicAdd(mycnt, 1);
                    if (off < MAXA) myidx[off] = e * 4 + b;
                }
            }
        };

        f32x4 va[8], vb[8];
        #pragma unroll
        for (int u = 0; u < 8; ++u)
            va[u] = __builtin_nontemporal_load(&s4[u * 64 + l]);
        #pragma unroll
        for (int c = 0; c < 6; c += 2) {
            #pragma unroll
            for (int u = 0; u < 8; ++u)
                vb[u] = __builtin_nontemporal_load(&s4[(c + 1) * 512 + u * 64 + l]);
            proc(va, c);
            if (c + 2 < 6) {
                #pragma unroll
                for (int u = 0; u < 8; ++u)
                    va[u] = __builtin_nontemporal_load(&s4[(c + 2) * 512 + u * 64 + l]);
            }
            proc(vb, c + 1);
        }
    }

    // ---- gather: lane l owns units 4l..4l+3; scalar (uniform) indices ----
    const int nW = min(cnt[w][0], MAXA);
    const int nB = min(cnt[w][1], MAXA);
    const float* ftl = ft + 4 * l;

    f32x4 a0 = {0.f,0.f,0.f,0.f}, a1 = a0, a2 = a0, a3 = a0;
    int i = 0;
    for (; i + 4 <= nW; i += 4) {
        const int i0 = __builtin_amdgcn_readfirstlane(idx[w][0][i]);
        const int i1 = __builtin_amdgcn_readfirstlane(idx[w][0][i + 1]);
        const int i2 = __builtin_amdgcn_readfirstlane(idx[w][0][i + 2]);
        const int i3 = __builtin_amdgcn_readfirstlane(idx[w][0][i + 3]);
        a0 += *(const f32x4*)(ftl + (size_t)i0 * H0);
        a1 += *(const f32x4*)(ftl + (size_t)i1 * H0);
        a2 += *(const f32x4*)(ftl + (size_t)i2 * H0);
        a3 += *(const f32x4*)(ftl + (size_t)i3 * H0);
    }
    for (; i < nW; ++i)
        a0 += *(const f32x4*)(ftl + (size_t)__builtin_amdgcn_readfirstlane(idx[w][0][i]) * H0);
    f32x4 accW = (a0 + a1) + (a2 + a3);

    f32x4 b0 = {0.f,0.f,0.f,0.f}, b1 = b0, b2 = b0, b3 = b0;
    i = 0;
    for (; i + 4 <= nB; i += 4) {
        const int i0 = __builtin_amdgcn_readfirstlane(idx[w][1][i]);
        const int i1 = __builtin_amdgcn_readfirstlane(idx[w][1][i + 1]);
        const int i2 = __builtin_amdgcn_readfirstlane(idx[w][1][i + 2]);
        const int i3 = __builtin_amdgcn_readfirstlane(idx[w][1][i + 3]);
        b0 += *(const f32x4*)(ftl + (size_t)i0 * H0);
        b1 += *(const f32x4*)(ftl + (size_t)i1 * H0);
        b2 += *(const f32x4*)(ftl + (size_t)i2 * H0);
        b3 += *(const f32x4*)(ftl + (size_t)i3 * H0);
    }
    for (; i < nB; ++i)
        b0 += *(const f32x4*)(ftl + (size_t)__builtin_amdgcn_readfirstlane(idx[w][1][i]) * H0);
    f32x4 accB = (b0 + b1) + (b2 + b3);

    // ---- bias + clamp + side-swapped concat into wave-private LDS ----
    const f32x4 ftb4 = *(const f32x4*)(ft_b + 4 * l);
    accW += ftb4;
    accB += ftb4;
    f32x4 wc, bc;
    wc.x = fminf(fmaxf(accW.x, 0.f), 1.f); wc.y = fminf(fmaxf(accW.y, 0.f), 1.f);
    wc.z = fminf(fmaxf(accW.z, 0.f), 1.f); wc.w = fminf(fmaxf(accW.w, 0.f), 1.f);
    bc.x = fminf(fmaxf(accB.x, 0.f), 1.f); bc.y = fminf(fmaxf(accB.y, 0.f), 1.f);
    bc.z = fminf(fmaxf(accB.z, 0.f), 1.f); bc.w = fminf(fmaxf(accB.w, 0.f), 1.f);
    const bool s = side[row] != 0;
    float* oseg = o0s[w];
    *(f32x4*)&oseg[(s ? 0 : H0) + 4 * l] = wc;
    *(f32x4*)&oseg[(s ? H0 : 0) + 4 * l] = bc;

    // ---- l1: 32 outs x 512 ins; 2 lanes/out; l1T[k*32+j] coalesced ----
    {
        const int j = l & 31, ph = l >> 5;
        const float* l1c = l1T + (ph * 256) * 32 + j;
        const float* ob  = oseg + ph * 256;
        float sum = 0.f;
        #pragma unroll 8
        for (int m2 = 0; m2 < 256; ++m2)
            sum += l1c[m2 * 32] * ob[m2];
        sum += __shfl_xor(sum, 32);
        if (l < 32)
            o1s[w][l] = fminf(fmaxf(sum + l1_b[l], 0.f), 1.f);
    }

    // ---- l2 (32x32, l2T coalesced) + l3 + sigmoid ----
    if (l < 32) {
        const float* l2c = l2T + l;
        float s2 = 0.f;
        #pragma unroll
        for (int k = 0; k < H1; ++k) s2 += l2c[k * 32] * o1s[w][k];
        const float o2v = fminf(fmaxf(s2 + l2_b[l], 0.f), 1.f);
        float part = o2v * l3_w[l];
        part += __shfl_xor(part, 1);
        part += __shfl_xor(part, 2);
        part += __shfl_xor(part, 4);
        part += __shfl_xor(part, 8);
        part += __shfl_xor(part, 16);
        if (l == 0) {
            const float o3 = (part + l3_b[0]) * OUT_SCALE;
            out[row] = 1.f / (1.f + __expf(-o3 / WDL_SCALE));
        }
    }
}

// ---------------------------------------------------------------------------
// Fallback (ws too small): round-5 fused kernel, untransposed strided gather.
// ---------------------------------------------------------------------------
__global__ __launch_bounds__(256) void nnue_fused_fallback(
    const float* __restrict__ wf, const float* __restrict__ bf,
    const int* __restrict__ side,
    const float* __restrict__ ft,        // ft_w [H0][NI]
    const float* __restrict__ ft_b,
    const float* __restrict__ l1_w, const float* __restrict__ l1_b,
    const float* __restrict__ l2_w, const float* __restrict__ l2_b,
    const float* __restrict__ l3_w, const float* __restrict__ l3_b,
    float* __restrict__ out)
{
    __shared__ int   idxW[MAXA], idxB[MAXA];
    __shared__ int   cnts[2];
    __shared__ float o0[2 * H0];
    __shared__ float o1[H1];

    const int row = blockIdx.x;
    const int t   = threadIdx.x;
    if (t < 2) cnts[t] = 0;
    __syncthreads();

    const f32x4* wf4 = (const f32x4*)(wf + (size_t)row * NI);
    const f32x4* bf4 = (const f32x4*)(bf + (size_t)row * NI);
    const float ftb = ft_b[t];

    for (int half = 0; half < 2; ++half) {
        const f32x4* p4 = half ? bf4 : wf4;
        int* lst = half ? idxB : idxW;
        f32x4 v[12];
        #pragma unroll
        for (int k = 0; k < 12; ++k)
            v[k] = __builtin_nontemporal_load(&p4[t + k * 256]);
        #pragma unroll
        for (int k = 0; k < 12; ++k) {
            const int base = (t + k * 256) * 4;
            int m = (v[k].x != 0.f ? 1 : 0) | (v[k].y != 0.f ? 2 : 0)
                  | (v[k].z != 0.f ? 4 : 0) | (v[k].w != 0.f ? 8 : 0);
            while (m) {
                const int b = __ffs(m) - 1;
                m &= m - 1;
                lst[atomicAdd(&cnts[half], 1)] = base + b;
            }
        }
    }
    __syncthreads();

    const int nW = cnts[0], nB = cnts[1];
    float accW = ftb, accB = ftb;
    const float* ftr = ft + (size_t)t * NI;
    for (int j = 0; j < nW; ++j) accW += ftr[idxW[j]];
    for (int j = 0; j < nB; ++j) accB += ftr[idxB[j]];

    const bool s = side[row] != 0;
    const float wv = fminf(fmaxf(accW, 0.f), 1.f);
    const float bv = fminf(fmaxf(accB, 0.f), 1.f);
    o0[t]      = s ? wv : bv;
    o0[t + H0] = s ? bv : wv;
    __syncthreads();

    {
        const int j = t >> 3, p = t & 7;
        const float* wrow = l1_w + j * (2 * H0);
        float sum = 0.f;
        #pragma unroll
        for (int m = 0; m < 64; ++m) sum += wrow[p + 8 * m] * o0[p + 8 * m];
        sum += __shfl_xor(sum, 1);
        sum += __shfl_xor(sum, 2);
        sum += __shfl_xor(sum, 4);
        if (p == 0) o1[j] = fminf(fmaxf(sum + l1_b[j], 0.f), 1.f);
    }
    __syncthreads();

    if (t < 32) {
        const float* wrow = l2_w + t * H1;
        float sum2 = 0.f;
        #pragma unroll
        for (int k = 0; k < H1; ++k) sum2 += wrow[k] * o1[k];
        const float o2v = fminf(fmaxf(sum2 + l2_b[t], 0.f), 1.f);
        float part = o2v * l3_w[t];
        part += __shfl_xor(part, 1);
        part += __shfl_xor(part, 2);
        part += __shfl_xor(part, 4);
        part += __shfl_xor(part, 8);
        part += __shfl_xor(part, 16);
        if (t == 0) {
            const float o3 = (part + l3_b[0]) * OUT_SCALE;
            out[row] = 1.f / (1.f + __expf(-o3 / WDL_SCALE));
        }
    }
}

extern "C" void kernel_launch(void* const* d_in, const int* in_sizes, int n_in,
                              void* d_out, int out_size, void* d_ws, size_t ws_size,
                              hipStream_t stream) {
    const float* wf   = (const float*)d_in[0];
    const float* bf   = (const float*)d_in[1];
    const int*   side = (const int*)d_in[2];
    const float* ft_w = (const float*)d_in[3];
    const float* ft_b = (const float*)d_in[4];
    const float* l1_w = (const float*)d_in[5];
    const float* l1_b = (const float*)d_in[6];
    const float* l2_w = (const float*)d_in[7];
    const float* l2_b = (const float*)d_in[8];
    const float* l3_w = (const float*)d_in[9];
    const float* l3_b = (const float*)d_in[10];
    float*       out  = (float*)d_out;

    if (ws_size >= WS_NEED) {
        float* ftT = (float*)d_ws;
        float* l1T = (float*)((char*)d_ws + FTT_B);
        float* l2T = (float*)((char*)d_ws + FTT_B + L1T_B);

        nnue_ft_transpose<<<dim3(NI / 64, H0 / 64), dim3(64, 4), 0, stream>>>(ft_w, ftT);
        nnue_small_transpose<<<(2 * H0 * H1 + H1 * H2 + 255) / 256, 256, 0, stream>>>(
            l1_w, l2_w, l1T, l2T);
        nnue_fwd_wave<<<NB / 4, 256, 0, stream>>>(wf, bf, side, ftT, ft_b,
                                                  l1T, l1_b, l2T, l2_b,
                                                  l3_w, l3_b, out);
    } else {
        nnue_fused_fallback<<<NB, 256, 0, stream>>>(wf, bf, side, ft_w, ft_b,
                                                    l1_w, l1_b, l2_w, l2_b,
                                                    l3_w, l3_b, out);
    }
}

// Round 8
// 165.292 us; speedup vs baseline: 1.3953x; 1.1878x over previous
//
#include <hip/hip_runtime.h>
#include <math.h>

#define NB 8192
#define NI 12288
#define H0 256
#define H1 32
#define H2 32
#define MAXA 256
#define OUT_SCALE 300.0f
#define WDL_SCALE 200.0f

typedef float          f32x4 __attribute__((ext_vector_type(4)));
typedef unsigned short u16x4 __attribute__((ext_vector_type(4)));

// ws layout: ftT_bf16 [NI][H0] (6,291,456 B)
#define FTT_B  ((size_t)NI * H0 * 2)
#define WS_NEED FTT_B

__device__ __forceinline__ unsigned short f2bf(float f) {
    unsigned u = __float_as_uint(f);
    u += 0x7FFFu + ((u >> 16) & 1u);          // round-to-nearest-even
    return (unsigned short)(u >> 16);
}
__device__ __forceinline__ f32x4 bf4_to_f32(u16x4 h) {
    f32x4 r;
    r.x = __uint_as_float(((unsigned)h.x) << 16);
    r.y = __uint_as_float(((unsigned)h.y) << 16);
    r.z = __uint_as_float(((unsigned)h.z) << 16);
    r.w = __uint_as_float(((unsigned)h.w) << 16);
    return r;
}

// ---------------------------------------------------------------------------
// Kernel 1: tiled transpose + bf16 convert: ft_w [H0][NI] f32 -> ftT [NI][H0] bf16
// ---------------------------------------------------------------------------
__global__ __launch_bounds__(256) void nnue_ft_transpose_bf16(
    const float* __restrict__ src, unsigned short* __restrict__ dst)
{
    __shared__ float tile[64][65];
    const int bx = blockIdx.x;               // NI/64
    const int by = blockIdx.y;               // H0/64
    const int tx = threadIdx.x;              // 64
    const int ty = threadIdx.y;              // 4
    const int col = bx * 64 + tx;
    for (int j = ty; j < 64; j += 4)
        tile[j][tx] = src[(size_t)(by * 64 + j) * NI + col];
    __syncthreads();
    const int h = by * 64 + tx;
    for (int j = ty; j < 64; j += 4)
        dst[(size_t)(bx * 64 + j) * H0 + h] = f2bf(tile[tx][j]);
}

// ---------------------------------------------------------------------------
// Kernel 2: fused forward, one 256-thread block per row (R5 structure).
// Phase A: white scan -> idxW.  Phase B: black NT prefetch issued FIRST, then
// wave-parallel white gather (bf16 table; vmcnt waits drain the older black
// loads for free => overlap), then black bit-scan -> idxB.  Phase C: black
// gather.  Then combine + side-swapped concat + 512->32->32->1 MLP + sigmoid.
// ---------------------------------------------------------------------------
__global__ __launch_bounds__(256) void nnue_fwd(
    const float* __restrict__ wf, const float* __restrict__ bf,
    const int* __restrict__ side,
    const unsigned short* __restrict__ ftb16,   // ftT [NI][H0] bf16
    const float* __restrict__ ft_b,
    const float* __restrict__ l1_w, const float* __restrict__ l1_b,
    const float* __restrict__ l2_w, const float* __restrict__ l2_b,
    const float* __restrict__ l3_w, const float* __restrict__ l3_b,
    float* __restrict__ out)
{
    __shared__ int   idxW[MAXA], idxB[MAXA];
    __shared__ int   cnts[2];
    __shared__ float pacc[4][2][H0] __attribute__((aligned(16)));
    __shared__ float o0[2 * H0];
    __shared__ float o1[H1];

    const int row = blockIdx.x;
    const int t   = threadIdx.x;
    if (t < 2) cnts[t] = 0;
    __syncthreads();

    const f32x4* wf4 = (const f32x4*)(wf + (size_t)row * NI);
    const f32x4* bf4 = (const f32x4*)(bf + (size_t)row * NI);

    // ---- Phase A: white scan (12-deep register prefetch) ----
    {
        f32x4 v[12];
        #pragma unroll
        for (int k = 0; k < 12; ++k)
            v[k] = __builtin_nontemporal_load(&wf4[t + k * 256]);
        #pragma unroll
        for (int k = 0; k < 12; ++k) {
            const int base = (t + k * 256) * 4;
            int m = (v[k].x != 0.f ? 1 : 0) | (v[k].y != 0.f ? 2 : 0)
                  | (v[k].z != 0.f ? 4 : 0) | (v[k].w != 0.f ? 8 : 0);
            while (m) {
                const int b = __ffs(m) - 1;
                m &= m - 1;
                idxW[atomicAdd(&cnts[0], 1)] = base + b;
            }
        }
    }
    __syncthreads();
    const int nW = cnts[0];

    const int w = t >> 6;                    // wave id 0..3
    const int l = t & 63;                    // lane
    const unsigned short* ftl = ftb16 + 4 * l;   // lane owns units 4l..4l+3

    // ---- Phase B: issue black prefetch FIRST, then white gather, then
    //      black bit-scan (black HBM latency hides under white gather) ----
    f32x4 u[12];
    #pragma unroll
    for (int k = 0; k < 12; ++k)
        u[k] = __builtin_nontemporal_load(&bf4[t + k * 256]);

    {
        f32x4 a0 = {0.f, 0.f, 0.f, 0.f}, a1 = a0;
        int i = w;
        for (; i + 4 < nW; i += 8) {         // wave w: features w, w+4, ...
            const int i0 = __builtin_amdgcn_readfirstlane(idxW[i]);
            const int i1 = __builtin_amdgcn_readfirstlane(idxW[i + 4]);
            const u16x4 h0 = *(const u16x4*)(ftl + (size_t)i0 * H0);
            const u16x4 h1 = *(const u16x4*)(ftl + (size_t)i1 * H0);
            a0 += bf4_to_f32(h0);
            a1 += bf4_to_f32(h1);
        }
        if (i < nW) {
            const int i0 = __builtin_amdgcn_readfirstlane(idxW[i]);
            a0 += bf4_to_f32(*(const u16x4*)(ftl + (size_t)i0 * H0));
        }
        *(f32x4*)&pacc[w][0][4 * l] = a0 + a1;
    }

    #pragma unroll
    for (int k = 0; k < 12; ++k) {
        const int base = (t + k * 256) * 4;
        int m = (u[k].x != 0.f ? 1 : 0) | (u[k].y != 0.f ? 2 : 0)
              | (u[k].z != 0.f ? 4 : 0) | (u[k].w != 0.f ? 8 : 0);
        while (m) {
            const int b = __ffs(m) - 1;
            m &= m - 1;
            idxB[atomicAdd(&cnts[1], 1)] = base + b;
        }
    }
    __syncthreads();
    const int nB = cnts[1];

    // ---- Phase C: black gather ----
    {
        f32x4 b0 = {0.f, 0.f, 0.f, 0.f}, b1 = b0;
        int i = w;
        for (; i + 4 < nB; i += 8) {
            const int i0 = __builtin_amdgcn_readfirstlane(idxB[i]);
            const int i1 = __builtin_amdgcn_readfirstlane(idxB[i + 4]);
            const u16x4 h0 = *(const u16x4*)(ftl + (size_t)i0 * H0);
            const u16x4 h1 = *(const u16x4*)(ftl + (size_t)i1 * H0);
            b0 += bf4_to_f32(h0);
            b1 += bf4_to_f32(h1);
        }
        if (i < nB) {
            const int i0 = __builtin_amdgcn_readfirstlane(idxB[i]);
            b0 += bf4_to_f32(*(const u16x4*)(ftl + (size_t)i0 * H0));
        }
        *(f32x4*)&pacc[w][1][4 * l] = b0 + b1;
    }
    __syncthreads();

    // ---- combine wave partials; side-swapped concat (thread t owns unit t) ----
    const float ftb  = ft_b[t];
    const float accW = ftb + ((pacc[0][0][t] + pacc[1][0][t]) + (pacc[2][0][t] + pacc[3][0][t]));
    const float accB = ftb + ((pacc[0][1][t] + pacc[1][1][t]) + (pacc[2][1][t] + pacc[3][1][t]));
    const bool s = side[row] != 0;
    const float wv = fminf(fmaxf(accW, 0.f), 1.f);
    const float bv = fminf(fmaxf(accB, 0.f), 1.f);
    o0[t]      = s ? wv : bv;
    o0[t + H0] = s ? bv : wv;
    __syncthreads();

    // ---- l1: 32 outputs x 512 inputs, 8 threads per output ----
    {
        const int j = t >> 3, p = t & 7;
        const float* wrow = l1_w + j * (2 * H0);
        float sum = 0.f;
        #pragma unroll
        for (int m = 0; m < 64; ++m) {
            const int k = p + 8 * m;         // stride-8: conflict-free LDS
            sum += wrow[k] * o0[k];
        }
        sum += __shfl_xor(sum, 1);
        sum += __shfl_xor(sum, 2);
        sum += __shfl_xor(sum, 4);
        if (p == 0) o1[j] = fminf(fmaxf(sum + l1_b[j], 0.f), 1.f);
    }
    __syncthreads();

    // ---- l2 (32x32) + l3 (1x32) + sigmoid ----
    if (t < 32) {
        const float* wrow = l2_w + t * H1;
        float sum2 = 0.f;
        #pragma unroll
        for (int k = 0; k < H1; ++k) sum2 += wrow[k] * o1[k];
        const float o2v = fminf(fmaxf(sum2 + l2_b[t], 0.f), 1.f);
        float part = o2v * l3_w[t];
        part += __shfl_xor(part, 1);
        part += __shfl_xor(part, 2);
        part += __shfl_xor(part, 4);
        part += __shfl_xor(part, 8);
        part += __shfl_xor(part, 16);
        if (t == 0) {
            const float o3 = (part + l3_b[0]) * OUT_SCALE;
            out[row] = 1.f / (1.f + __expf(-o3 / WDL_SCALE));
        }
    }
}

// ---------------------------------------------------------------------------
// Fallback (ws too small): fused kernel, untransposed strided fp32 gather.
// ---------------------------------------------------------------------------
__global__ __launch_bounds__(256) void nnue_fused_fallback(
    const float* __restrict__ wf, const float* __restrict__ bf,
    const int* __restrict__ side,
    const float* __restrict__ ft,        // ft_w [H0][NI]
    const float* __restrict__ ft_b,
    const float* __restrict__ l1_w, const float* __restrict__ l1_b,
    const float* __restrict__ l2_w, const float* __restrict__ l2_b,
    const float* __restrict__ l3_w, const float* __restrict__ l3_b,
    float* __restrict__ out)
{
    __shared__ int   idxW[MAXA], idxB[MAXA];
    __shared__ int   cnts[2];
    __shared__ float o0[2 * H0];
    __shared__ float o1[H1];

    const int row = blockIdx.x;
    const int t   = threadIdx.x;
    if (t < 2) cnts[t] = 0;
    __syncthreads();

    const f32x4* wf4 = (const f32x4*)(wf + (size_t)row * NI);
    const f32x4* bf4 = (const f32x4*)(bf + (size_t)row * NI);
    const float ftb = ft_b[t];

    for (int half = 0; half < 2; ++half) {
        const f32x4* p4 = half ? bf4 : wf4;
        int* lst = half ? idxB : idxW;
        f32x4 v[12];
        #pragma unroll
        for (int k = 0; k < 12; ++k)
            v[k] = __builtin_nontemporal_load(&p4[t + k * 256]);
        #pragma unroll
        for (int k = 0; k < 12; ++k) {
            const int base = (t + k * 256) * 4;
            int m = (v[k].x != 0.f ? 1 : 0) | (v[k].y != 0.f ? 2 : 0)
                  | (v[k].z != 0.f ? 4 : 0) | (v[k].w != 0.f ? 8 : 0);
            while (m) {
                const int b = __ffs(m) - 1;
                m &= m - 1;
                lst[atomicAdd(&cnts[half], 1)] = base + b;
            }
        }
    }
    __syncthreads();

    const int nW = cnts[0], nB = cnts[1];
    float accW = ftb, accB = ftb;
    const float* ftr = ft + (size_t)t * NI;
    for (int j = 0; j < nW; ++j) accW += ftr[idxW[j]];
    for (int j = 0; j < nB; ++j) accB += ftr[idxB[j]];

    const bool s = side[row] != 0;
    const float wv = fminf(fmaxf(accW, 0.f), 1.f);
    const float bv = fminf(fmaxf(accB, 0.f), 1.f);
    o0[t]      = s ? wv : bv;
    o0[t + H0] = s ? bv : wv;
    __syncthreads();

    {
        const int j = t >> 3, p = t & 7;
        const float* wrow = l1_w + j * (2 * H0);
        float sum = 0.f;
        #pragma unroll
        for (int m = 0; m < 64; ++m) sum += wrow[p + 8 * m] * o0[p + 8 * m];
        sum += __shfl_xor(sum, 1);
        sum += __shfl_xor(sum, 2);
        sum += __shfl_xor(sum, 4);
        if (p == 0) o1[j] = fminf(fmaxf(sum + l1_b[j], 0.f), 1.f);
    }
    __syncthreads();

    if (t < 32) {
        const float* wrow = l2_w + t * H1;
        float sum2 = 0.f;
        #pragma unroll
        for (int k = 0; k < H1; ++k) sum2 += wrow[k] * o1[k];
        const float o2v = fminf(fmaxf(sum2 + l2_b[t], 0.f), 1.f);
        float part = o2v * l3_w[t];
        part += __shfl_xor(part, 1);
        part += __shfl_xor(part, 2);
        part += __shfl_xor(part, 4);
        part += __shfl_xor(part, 8);
        part += __shfl_xor(part, 16);
        if (t == 0) {
            const float o3 = (part + l3_b[0]) * OUT_SCALE;
            out[row] = 1.f / (1.f + __expf(-o3 / WDL_SCALE));
        }
    }
}

extern "C" void kernel_launch(void* const* d_in, const int* in_sizes, int n_in,
                              void* d_out, int out_size, void* d_ws, size_t ws_size,
                              hipStream_t stream) {
    const float* wf   = (const float*)d_in[0];
    const float* bf   = (const float*)d_in[1];
    const int*   side = (const int*)d_in[2];
    const float* ft_w = (const float*)d_in[3];
    const float* ft_b = (const float*)d_in[4];
    const float* l1_w = (const float*)d_in[5];
    const float* l1_b = (const float*)d_in[6];
    const float* l2_w = (const float*)d_in[7];
    const float* l2_b = (const float*)d_in[8];
    const float* l3_w = (const float*)d_in[9];
    const float* l3_b = (const float*)d_in[10];
    float*       out  = (float*)d_out;

    if (ws_size >= WS_NEED) {
        unsigned short* ftT = (unsigned short*)d_ws;
        nnue_ft_transpose_bf16<<<dim3(NI / 64, H0 / 64), dim3(64, 4), 0, stream>>>(ft_w, ftT);
        nnue_fwd<<<NB, 256, 0, stream>>>(wf, bf, side, ftT, ft_b,
                                         l1_w, l1_b, l2_w, l2_b, l3_w, l3_b, out);
    } else {
        nnue_fused_fallback<<<NB, 256, 0, stream>>>(wf, bf, side, ft_w, ft_b,
                                                    l1_w, l1_b, l2_w, l2_b,
                                                    l3_w, l3_b, out);
    }
}